// Round 22
// baseline (312.241 us; speedup 1.0000x reference)
//
#include <hip/hip_runtime.h>
#include <hip/hip_bf16.h>
#include <math.h>

typedef __bf16 bf16;
typedef __bf16 bf16x4 __attribute__((ext_vector_type(4)));
typedef __bf16 bf16x8 __attribute__((ext_vector_type(8)));
typedef float  f32x4  __attribute__((ext_vector_type(4)));

#define DEVI static __device__ __forceinline__

constexpr int B_ = 32, N_ = 4096, NS_ = 11, SP_ = 16, ITERS_ = 3;
constexpr int P_ = 32;
constexpr float LN_EPS_ = 1e-3f;
constexpr float EPS_ATTN_ = 1e-8f;

DEVI f32x4 mfma16(bf16x8 a, bf16x8 b, f32x4 c) {
  return __builtin_amdgcn_mfma_f32_16x16x32_bf16(a, b, c, 0, 0, 0);
}

DEVI float wsum64(float v) {
#pragma unroll
  for (int m = 32; m > 0; m >>= 1) v += __shfl_xor(v, m, 64);
  return v;
}

// ---------------- weight cast (fp32 -> bf16) ----------------
__global__ __launch_bounds__(256) void cast_weights(
    const float* __restrict__ Wq, const float* __restrict__ Wk,
    const float* __restrict__ Wv, const float* __restrict__ Wih,
    const float* __restrict__ Whh, const float* __restrict__ W1,
    const float* __restrict__ W2,
    bf16* __restrict__ cWkT, bf16* __restrict__ cWvT, bf16* __restrict__ cWq,
    bf16* __restrict__ cWih, bf16* __restrict__ cWhh, bf16* __restrict__ cW1,
    bf16* __restrict__ cW2) {
  const int idx = blockIdx.x * 256 + threadIdx.x;
  const int n0 = 256 * 256;            // cWkT (transposed)
  const int n1 = n0 + 256 * 256;       // cWvT (transposed)
  const int n2 = n1 + 256 * 256;       // cWq
  const int n3 = n2 + 768 * 256;       // cWih
  const int n4 = n3 + 768 * 256;       // cWhh
  const int n5 = n4 + 512 * 256;       // cW1
  const int n6 = n5 + 256 * 512;       // cW2   (total 851968 = 3328*256)
  if (idx < n0) {
    const int c = idx >> 8, d = idx & 255;
    cWkT[idx] = (bf16)Wk[d * 256 + c];
  } else if (idx < n1) {
    const int i = idx - n0; const int c = i >> 8, d = i & 255;
    cWvT[i] = (bf16)Wv[d * 256 + c];
  } else if (idx < n2) { const int i = idx - n1; cWq[i]  = (bf16)Wq[i];
  } else if (idx < n3) { const int i = idx - n2; cWih[i] = (bf16)Wih[i];
  } else if (idx < n4) { const int i = idx - n3; cWhh[i] = (bf16)Whh[i];
  } else if (idx < n5) { const int i = idx - n4; cW1[i]  = (bf16)W1[i];
  } else if (idx < n6) { const int i = idx - n5; cW2[i]  = (bf16)W2[i]; }
}

// ---------------- Wfold = Wih @ Wv  (768x256, K=256) ----------------
__global__ __launch_bounds__(256) void wfold_gemm(
    const bf16* __restrict__ Wih, const bf16* __restrict__ WvT,
    bf16* __restrict__ Wfold) {
  __shared__ bf16 At[32 * 256];                  // 16 KiB
  const int mt = blockIdx.x, nt = blockIdx.y;    // (24, 4)
  const int tid = threadIdx.x, lane = tid & 63, wid = tid >> 6;
  const int l15 = lane & 15, gq = lane >> 4;
  const bf16* A = Wih + (size_t)mt * 32 * 256;
#pragma unroll
  for (int i = 0; i < 4; ++i) {
    const int idx = i * 256 + tid, row = idx >> 5, c = idx & 31;
    const bf16x8 v = *(const bf16x8*)(A + row * 256 + c * 8);
    const int byte = (row * 512 + c * 16) ^ ((row & 7) << 4);
    *(bf16x8*)((char*)At + byte) = v;
  }
  __syncthreads();
  const int wr = wid >> 1, wc = wid & 1;
  f32x4 acc[2] = {};
  for (int kk = 0; kk < 8; ++kk) {
    const int arow = wr * 16 + l15;
    const int byte = (arow * 512 + kk * 64 + gq * 16) ^ ((arow & 7) << 4);
    const bf16x8 af = *(const bf16x8*)((const char*)At + byte);
#pragma unroll
    for (int nn = 0; nn < 2; ++nn) {
      const bf16* wrow = WvT + (size_t)(nt * 64 + wc * 32 + nn * 16 + l15) * 256 + kk * 32 + gq * 8;
      acc[nn] = mfma16(af, *(const bf16x8*)wrow, acc[nn]);
    }
  }
#pragma unroll
  for (int nn = 0; nn < 2; ++nn)
#pragma unroll
    for (int r = 0; r < 4; ++r) {
      const int grow = mt * 32 + wr * 16 + gq * 4 + r;
      const int col = nt * 64 + wc * 32 + nn * 16 + l15;
      Wfold[(size_t)grow * 256 + col] = (bf16)acc[nn][r];
    }
}

// ---------------- slot init: fp32 + bf16 copies ----------------
__global__ __launch_bounds__(256) void init_slots(
    const float* __restrict__ mu, const float* __restrict__ lsig,
    const float* __restrict__ noise, float* __restrict__ slots,
    bf16* __restrict__ slots_bf) {
  const int idx = blockIdx.x * 256 + threadIdx.x;  // 90112 exact
  const int d = idx & 255;
  const float v = mu[d] + expf(lsig[d]) * noise[idx];
  slots[idx] = v;
  slots_bf[idx] = (bf16)v;
}

// ---------------- pure-streaming LN: fp32 inputs -> bf16 xhat ----------------
__global__ __launch_bounds__(256) void ln_cast(
    const float* __restrict__ inp, const float* __restrict__ g,
    const float* __restrict__ be, bf16* __restrict__ xhat) {
  const int tid = threadIdx.x, lane = tid & 63, wid = tid >> 6;
  const int l15 = lane & 15, gq = lane >> 4;
  float4 gv[4], bv4[4];
#pragma unroll
  for (int u = 0; u < 4; ++u) {
    gv[u]  = ((const float4*)g)[l15 * 4 + u];
    bv4[u] = ((const float4*)be)[l15 * 4 + u];
  }
  const int nwaves = gridDim.x * 4;
  const int gw = blockIdx.x * 4 + wid;
  for (int qi = gw; qi < (B_ * N_ / 4); qi += nwaves) {
    const size_t grow = (size_t)qi * 4 + gq;
    const float4* rp = (const float4*)(inp + grow * 256 + l15 * 16);
    float4 x[4];
#pragma unroll
    for (int u = 0; u < 4; ++u) x[u] = rp[u];
    float s = 0.f, ss = 0.f;
#pragma unroll
    for (int u = 0; u < 4; ++u) {
      s += x[u].x + x[u].y + x[u].z + x[u].w;
      ss = fmaf(x[u].x, x[u].x, fmaf(x[u].y, x[u].y,
           fmaf(x[u].z, x[u].z, fmaf(x[u].w, x[u].w, ss))));
    }
#pragma unroll
    for (int m = 8; m > 0; m >>= 1) {
      s  += __shfl_xor(s,  m, 16);
      ss += __shfl_xor(ss, m, 16);
    }
    const float mean = s * (1.f / 256.f);
    const float rstd = rsqrtf(ss * (1.f / 256.f) - mean * mean + LN_EPS_);
    bf16x8 y0, y1;
#pragma unroll
    for (int u = 0; u < 2; ++u) {
      y0[u * 4 + 0] = (bf16)((x[u].x - mean) * rstd * gv[u].x + bv4[u].x);
      y0[u * 4 + 1] = (bf16)((x[u].y - mean) * rstd * gv[u].y + bv4[u].y);
      y0[u * 4 + 2] = (bf16)((x[u].z - mean) * rstd * gv[u].z + bv4[u].z);
      y0[u * 4 + 3] = (bf16)((x[u].w - mean) * rstd * gv[u].w + bv4[u].w);
      y1[u * 4 + 0] = (bf16)((x[2+u].x - mean) * rstd * gv[2+u].x + bv4[2+u].x);
      y1[u * 4 + 1] = (bf16)((x[2+u].y - mean) * rstd * gv[2+u].y + bv4[2+u].y);
      y1[u * 4 + 2] = (bf16)((x[2+u].z - mean) * rstd * gv[2+u].z + bv4[2+u].z);
      y1[u * 4 + 3] = (bf16)((x[2+u].w - mean) * rstd * gv[2+u].w + bv4[2+u].w);
    }
    bf16* orow = xhat + grow * 256 + l15 * 16;
    *(bf16x8*)orow       = y0;
    *(bf16x8*)(orow + 8) = y1;
  }
}

// ---------------- q~ projection: LN(slots) @ Wq^T @ Wk ----------------
__global__ __launch_bounds__(256) void q_proj(
    const float* __restrict__ slots, const float* __restrict__ g,
    const float* __restrict__ be, const bf16* __restrict__ Wqb,
    const bf16* __restrict__ WkT, bf16* __restrict__ qpad) {
  const int i = blockIdx.x, b = blockIdx.y, t = threadIdx.x;
  bf16* out = qpad + (b * SP_ + i) * 256;
  if (i >= NS_) { out[t] = (bf16)0.f; return; }
  __shared__ float lnv[256], qd[256];
  __shared__ float red[8];
  const float x = slots[(b * NS_ + i) * 256 + t];
  float s = wsum64(x), ss = wsum64(x * x);
  const int lane = t & 63, w = t >> 6;
  if (lane == 0) { red[w] = s; red[4 + w] = ss; }
  __syncthreads();
  const float st = red[0] + red[1] + red[2] + red[3];
  const float qt = red[4] + red[5] + red[6] + red[7];
  const float mean = st / 256.f, var = qt / 256.f - mean * mean;
  const float rstd = rsqrtf(var + LN_EPS_);
  lnv[t] = (x - mean) * rstd * g[t] + be[t];
  __syncthreads();
  {
    float acc = 0.f;
    const bf16* wr = Wqb + (size_t)t * 256;
    for (int it = 0; it < 32; ++it) {
      const bf16x8 wv = *(const bf16x8*)(wr + it * 8);
      const float* u = &lnv[it * 8];
#pragma unroll
      for (int e = 0; e < 8; ++e) acc += (float)wv[e] * u[e];
    }
    qd[t] = acc;
  }
  __syncthreads();
  {
    float acc = 0.f;
    const bf16* wr = WkT + (size_t)t * 256;
    for (int it = 0; it < 32; ++it) {
      const bf16x8 wv = *(const bf16x8*)(wr + it * 8);
      const float* u = &qd[it * 8];
#pragma unroll
      for (int e = 0; e < 8; ++e) acc += (float)wv[e] * u[e];
    }
    out[t] = (bf16)(acc * 0.0625f);
  }
}

// ---------------- fused attention partial pass (V staged; bf16 nsw) --------
// grid (P_, B), 256 threads; LDS 48 KiB -> 3 blocks/CU.
__global__ __launch_bounds__(256) void attn_part(
    const bf16* __restrict__ xhat, const bf16* __restrict__ qpad,
    bf16* __restrict__ num_part, float* __restrict__ den_part) {
  const int part = blockIdx.x, b = blockIdx.y;
  const int lane = threadIdx.x & 63, wid = threadIdx.x >> 6;
  const int l15 = lane & 15, gq = lane >> 4;
  const int jbase = part * 128 + wid * 32;
  const bf16* qrow = qpad + ((size_t)(b * SP_ + l15)) * 256;
  const bf16* kbase = xhat + ((size_t)(b * N_ + jbase)) * 256;
  __shared__ bf16 vlds[4][4096];                 // 32 KiB (8 KiB / wave)
  __shared__ bf16 nsw[2][4096];                  // 16 KiB (bf16 partials)
  __shared__ float dens[4][16];
  char* myv = (char*)&vlds[wid][0];
  const int srow = gq;

  // issue V half-0 loads (c 0..127): hidden under QK^T
  bf16x8 vst[8];
#pragma unroll
  for (int i = 0; i < 8; ++i)
    vst[i] = *(const bf16x8*)(kbase + (size_t)(i * 4 + srow) * 256 + l15 * 8);
  // hoisted q fragments
  bf16x8 bq[8];
#pragma unroll
  for (int kk = 0; kk < 8; ++kk)
    bq[kk] = *(const bf16x8*)(qrow + kk * 32 + gq * 8);

  float denacc = 0.f;
  float p0[4], p1[4];
#pragma unroll
  for (int T = 0; T < 2; ++T) {
    const bf16* krow = kbase + (size_t)(T * 16 + l15) * 256;
    f32x4 d = {0.f, 0.f, 0.f, 0.f};
#pragma unroll
    for (int kk = 0; kk < 8; ++kk) {
      const bf16x8 ak = *(const bf16x8*)(krow + kk * 32 + gq * 8);
      d = mfma16(ak, bq[kk], d);
    }
#pragma unroll
    for (int r = 0; r < 4; ++r) {
      float vmax = (l15 < NS_) ? d[r] : -1e30f;
#pragma unroll
      for (int mm = 8; mm > 0; mm >>= 1) vmax = fmaxf(vmax, __shfl_xor(vmax, mm, 16));
      const float e = (l15 < NS_) ? expf(d[r] - vmax) : 0.f;
      float ssum = e;
#pragma unroll
      for (int mm = 8; mm > 0; mm >>= 1) ssum += __shfl_xor(ssum, mm, 16);
      const float p = (l15 < NS_) ? (e / ssum + EPS_ATTN_) : 0.f;
      if (T == 0) p0[r] = p; else p1[r] = p;
      denacc += p;
    }
  }
  // regather P into A-frag layout
  bf16x8 ap;
#pragma unroll
  for (int e = 0; e < 8; ++e) {
    const int srcl = l15 + ((2 * (gq & 1) + (e >> 2)) << 4);
    const float va = __shfl(p0[e & 3], srcl, 64);
    const float vb = __shfl(p1[e & 3], srcl, 64);
    ap[e] = (bf16)((gq < 2) ? va : vb);
  }
  // --- PV with V through per-wave swizzled LDS, two c-halves of 128 ---
  f32x4 accN[16];
#pragma unroll
  for (int i = 0; i < 8; ++i) {                  // ds_write half 0
    const int row = i * 4 + srow;
    const int byte = (row * 256 + l15 * 16) ^ ((((row >> 3) & 3)) << 5);
    *(bf16x8*)(myv + byte) = vst[i];
  }
#pragma unroll
  for (int i = 0; i < 8; ++i)                    // issue half-1 loads
    vst[i] = *(const bf16x8*)(kbase + (size_t)(i * 4 + srow) * 256 + 128 + l15 * 8);
  __builtin_amdgcn_s_setprio(1);
#pragma unroll
  for (int l = 0; l < 8; ++l) {                  // PV c-blk 0..7
    bf16x8 bvf;
#pragma unroll
    for (int e = 0; e < 8; ++e) {
      const int row = 8 * gq + e;
      const int byte = (row * 256 + l * 32 + l15 * 2) ^ ((((row >> 3) & 3)) << 5);
      bvf[e] = *(const bf16*)(myv + byte);
    }
    f32x4 z = {0.f, 0.f, 0.f, 0.f};
    accN[l] = mfma16(ap, bvf, z);
  }
  __builtin_amdgcn_s_setprio(0);
#pragma unroll
  for (int i = 0; i < 8; ++i) {                  // ds_write half 1
    const int row = i * 4 + srow;
    const int byte = (row * 256 + l15 * 16) ^ ((((row >> 3) & 3)) << 5);
    *(bf16x8*)(myv + byte) = vst[i];
  }
  __builtin_amdgcn_s_setprio(1);
#pragma unroll
  for (int l = 0; l < 8; ++l) {                  // PV c-blk 8..15
    bf16x8 bvf;
#pragma unroll
    for (int e = 0; e < 8; ++e) {
      const int row = 8 * gq + e;
      const int byte = (row * 256 + l * 32 + l15 * 2) ^ ((((row >> 3) & 3)) << 5);
      bvf[e] = *(const bf16*)(myv + byte);
    }
    f32x4 z = {0.f, 0.f, 0.f, 0.f};
    accN[8 + l] = mfma16(ap, bvf, z);
  }
  __builtin_amdgcn_s_setprio(0);
  // cross-wave reduce (bf16 partials in LDS)
  if (wid < 2) {
#pragma unroll
    for (int dblk = 0; dblk < 16; ++dblk)
#pragma unroll
      for (int r = 0; r < 4; ++r) {
        const int idx = (((4 * gq + r) * 256) + dblk * 16 + l15) ^ (gq << 4);
        nsw[wid][idx] = (bf16)accN[dblk][r];
      }
  }
  __syncthreads();
  if (wid >= 2) {
#pragma unroll
    for (int dblk = 0; dblk < 16; ++dblk)
#pragma unroll
      for (int r = 0; r < 4; ++r) {
        const int idx = (((4 * gq + r) * 256) + dblk * 16 + l15) ^ (gq << 4);
        nsw[wid - 2][idx] = (bf16)((float)nsw[wid - 2][idx] + accN[dblk][r]);
      }
  }
  float dtot = denacc + __shfl_xor(denacc, 16, 64);
  dtot += __shfl_xor(dtot, 32, 64);
  if (lane < 16) dens[wid][l15] = dtot;
  __syncthreads();
  const int t = threadIdx.x;
  if (t < NS_)
    den_part[(b * P_ + part) * NS_ + t] =
        dens[0][t] + dens[1][t] + dens[2][t] + dens[3][t];
  for (int r = 0; r < NS_; ++r) {
    const int swz = ((r >> 2) & 3) << 4;
    num_part[((size_t)((b * P_ + part) * NS_ + r)) * 256 + t] =
        (bf16)((float)nsw[0][(r * 256 + t) ^ swz] + (float)nsw[1][(r * 256 + t) ^ swz]);
  }
}

// ---------------- u0 reduce: bf16 num_part/den -> bf16 (352x256) -----------
__global__ __launch_bounds__(256) void u0_reduce(
    const bf16* __restrict__ num_part, const float* __restrict__ den_part,
    bf16* __restrict__ u0b) {
  const int row = blockIdx.x, t = threadIdx.x;
  const int b = row / NS_, i = row % NS_;
  float nsum = 0.f;
  for (int p = 0; p < P_; ++p)
    nsum += (float)num_part[((size_t)((b * P_ + p) * NS_ + i)) * 256 + t];
  float den = 0.f;
  for (int p = 0; p < P_; ++p) den += den_part[(b * P_ + p) * NS_ + i];
  u0b[(size_t)row * 256 + t] = (bf16)(nsum / den);
}

// ---------------- fused gates GEMM + GRU elementwise ----------------
// grid (11, 4): block = 32 rows x 64 cols; in-register gi/gh for all 3
// gate-thirds; sigmoid/tanh lane-local; writes hn (f32) only.
__global__ __launch_bounds__(256) void gates_ew(
    const bf16* __restrict__ u0b, const bf16* __restrict__ hb,
    const bf16* __restrict__ Wfold, const bf16* __restrict__ Whh,
    const float* __restrict__ bih, const float* __restrict__ bhh,
    const float* __restrict__ slots_f, float* __restrict__ hn_out) {
  __shared__ bf16 Au[32 * 256];                  // 16 KiB
  __shared__ bf16 Ah[32 * 256];                  // 16 KiB
  const int mt = blockIdx.x, nt = blockIdx.y;
  const int tid = threadIdx.x, lane = tid & 63, wid = tid >> 6;
  const int l15 = lane & 15, gq = lane >> 4;
#pragma unroll
  for (int i = 0; i < 4; ++i) {
    const int idx = i * 256 + tid, row = idx >> 5, c = idx & 31;
    const int byte = (row * 512 + c * 16) ^ ((row & 7) << 4);
    *(bf16x8*)((char*)Au + byte) =
        *(const bf16x8*)(u0b + (size_t)(mt * 32 + row) * 256 + c * 8);
    *(bf16x8*)((char*)Ah + byte) =
        *(const bf16x8*)(hb + (size_t)(mt * 32 + row) * 256 + c * 8);
  }
  __syncthreads();
  const int wr = wid >> 1, wc = wid & 1;
  f32x4 ai[3][2] = {}, ah[3][2] = {};
  for (int kk = 0; kk < 8; ++kk) {
    const int arow = wr * 16 + l15;
    const int byte = (arow * 512 + kk * 64 + gq * 16) ^ ((arow & 7) << 4);
    const bf16x8 au = *(const bf16x8*)((const char*)Au + byte);
    const bf16x8 av = *(const bf16x8*)((const char*)Ah + byte);
#pragma unroll
    for (int ggt = 0; ggt < 3; ++ggt)
#pragma unroll
      for (int tc = 0; tc < 2; ++tc) {
        const size_t wrow = (size_t)(ggt * 256 + nt * 64 + wc * 32 + tc * 16 + l15) * 256 + kk * 32 + gq * 8;
        ai[ggt][tc] = mfma16(au, *(const bf16x8*)(Wfold + wrow), ai[ggt][tc]);
        ah[ggt][tc] = mfma16(av, *(const bf16x8*)(Whh + wrow), ah[ggt][tc]);
      }
  }
  // elementwise GRU, lane-local (C layout: col=l15, row=gq*4+r)
#pragma unroll
  for (int tc = 0; tc < 2; ++tc) {
    const int col = nt * 64 + wc * 32 + tc * 16 + l15;
    const float bir = bih[col],        bhr = bhh[col];
    const float biz = bih[256 + col],  bhz = bhh[256 + col];
    const float bin = bih[512 + col],  bhn = bhh[512 + col];
#pragma unroll
    for (int r = 0; r < 4; ++r) {
      const int grow = mt * 32 + wr * 16 + gq * 4 + r;
      const float ir = ai[0][tc][r] + bir, hr = ah[0][tc][r] + bhr;
      const float iz = ai[1][tc][r] + biz, hz = ah[1][tc][r] + bhz;
      const float inn = ai[2][tc][r] + bin, hnn = ah[2][tc][r] + bhn;
      const float h = slots_f[(size_t)grow * 256 + col];
      const float rg = 1.f / (1.f + expf(-(ir + hr)));
      const float zg = 1.f / (1.f + expf(-(iz + hz)));
      const float ng = tanhf(inn + rg * hnn);
      hn_out[(size_t)grow * 256 + col] = (1.f - zg) * ng + zg * h;
    }
  }
}

// ---------------- W1 GEMM with fused LN on staging ----------------
// grid (11, 8). Stages hn (f32), computes per-row LN redundantly, LDS bf16.
__global__ __launch_bounds__(256) void w1_gemm(
    const float* __restrict__ hn_f, const float* __restrict__ gff,
    const float* __restrict__ beff, const bf16* __restrict__ W1,
    const float* __restrict__ b1, bf16* __restrict__ h1b) {
  __shared__ bf16 At[32 * 256];
  const int mt = blockIdx.x, nt = blockIdx.y;
  const int tid = threadIdx.x, lane = tid & 63, wid = tid >> 6;
  const int l15 = lane & 15, gq = lane >> 4;
#pragma unroll
  for (int i = 0; i < 4; ++i) {
    const int idx = i * 256 + tid, row = idx >> 5, c = idx & 31;
    const float* src = hn_f + (size_t)(mt * 32 + row) * 256 + c * 8;
    const float4 f0 = ((const float4*)src)[0];
    const float4 f1 = ((const float4*)src)[1];
    float s  = f0.x + f0.y + f0.z + f0.w + f1.x + f1.y + f1.z + f1.w;
    float ss = fmaf(f0.x, f0.x, fmaf(f0.y, f0.y, fmaf(f0.z, f0.z,
               fmaf(f0.w, f0.w, fmaf(f1.x, f1.x, fmaf(f1.y, f1.y,
               fmaf(f1.z, f1.z, f1.w * f1.w)))))));
    // reduce across the 32 threads sharing this row (lane halves of 32)
#pragma unroll
    for (int m = 16; m > 0; m >>= 1) {
      s  += __shfl_xor(s,  m, 32);
      ss += __shfl_xor(ss, m, 32);
    }
    const float mean = s * (1.f / 256.f);
    const float rstd = rsqrtf(ss * (1.f / 256.f) - mean * mean + LN_EPS_);
    bf16x8 y;
    const float* gp = gff + c * 8;
    const float* bp = beff + c * 8;
    y[0] = (bf16)((f0.x - mean) * rstd * gp[0] + bp[0]);
    y[1] = (bf16)((f0.y - mean) * rstd * gp[1] + bp[1]);
    y[2] = (bf16)((f0.z - mean) * rstd * gp[2] + bp[2]);
    y[3] = (bf16)((f0.w - mean) * rstd * gp[3] + bp[3]);
    y[4] = (bf16)((f1.x - mean) * rstd * gp[4] + bp[4]);
    y[5] = (bf16)((f1.y - mean) * rstd * gp[5] + bp[5]);
    y[6] = (bf16)((f1.z - mean) * rstd * gp[6] + bp[6]);
    y[7] = (bf16)((f1.w - mean) * rstd * gp[7] + bp[7]);
    const int byte = (row * 512 + c * 16) ^ ((row & 7) << 4);
    *(bf16x8*)((char*)At + byte) = y;
  }
  __syncthreads();
  const int wr = wid >> 1, wc = wid & 1;
  f32x4 acc[2] = {};
  for (int kk = 0; kk < 8; ++kk) {
    const int arow = wr * 16 + l15;
    const int byte = (arow * 512 + kk * 64 + gq * 16) ^ ((arow & 7) << 4);
    const bf16x8 af = *(const bf16x8*)((const char*)At + byte);
#pragma unroll
    for (int nn = 0; nn < 2; ++nn) {
      const bf16* wrow = W1 + (size_t)(nt * 64 + wc * 32 + nn * 16 + l15) * 256 + kk * 32 + gq * 8;
      acc[nn] = mfma16(af, *(const bf16x8*)wrow, acc[nn]);
    }
  }
#pragma unroll
  for (int nn = 0; nn < 2; ++nn)
#pragma unroll
    for (int r = 0; r < 4; ++r) {
      const int grow = mt * 32 + wr * 16 + gq * 4 + r;
      const int col = nt * 64 + wc * 32 + nn * 16 + l15;
      h1b[(size_t)grow * 512 + col] = (bf16)fmaxf(acc[nn][r] + b1[col], 0.f);
    }
}

// ---------------- W2 GEMM (K=512): out = hn + h1@W2^T + b2 ----------------
__global__ __launch_bounds__(256) void w2_gemm(
    const bf16* __restrict__ h1b, const bf16* __restrict__ W2,
    const float* __restrict__ b2, const float* __restrict__ hn_in,
    float* __restrict__ sout, bf16* __restrict__ sbf) {
  __shared__ bf16 At[32 * 512];                  // 32 KiB
  const int mt = blockIdx.x, nt = blockIdx.y;    // (11, 4)
  const int tid = threadIdx.x, lane = tid & 63, wid = tid >> 6;
  const int l15 = lane & 15, gq = lane >> 4;
  const bf16* A = h1b + (size_t)mt * 32 * 512;
#pragma unroll
  for (int i = 0; i < 8; ++i) {
    const int idx = i * 256 + tid, row = idx >> 6, c = idx & 63;
    const bf16x8 v = *(const bf16x8*)(A + row * 512 + c * 8);
    const int byte = (row * 1024 + c * 16) ^ ((row & 7) << 4);
    *(bf16x8*)((char*)At + byte) = v;
  }
  __syncthreads();
  const int wr = wid >> 1, wc = wid & 1;
  f32x4 acc[2] = {};
  for (int kk = 0; kk < 16; ++kk) {
    const int arow = wr * 16 + l15;
    const int byte = (arow * 1024 + kk * 64 + gq * 16) ^ ((arow & 7) << 4);
    const bf16x8 af = *(const bf16x8*)((const char*)At + byte);
#pragma unroll
    for (int nn = 0; nn < 2; ++nn) {
      const bf16* wrow = W2 + (size_t)(nt * 64 + wc * 32 + nn * 16 + l15) * 512 + kk * 32 + gq * 8;
      acc[nn] = mfma16(af, *(const bf16x8*)wrow, acc[nn]);
    }
  }
#pragma unroll
  for (int nn = 0; nn < 2; ++nn)
#pragma unroll
    for (int r = 0; r < 4; ++r) {
      const int grow = mt * 32 + wr * 16 + gq * 4 + r;
      const int col = nt * 64 + wc * 32 + nn * 16 + l15;
      const float v = hn_in[(size_t)grow * 256 + col] + acc[nn][r] + b2[col];
      sout[(size_t)grow * 256 + col] = v;
      sbf[(size_t)grow * 256 + col] = (bf16)v;
    }
}

// ---------------- launcher ----------------
extern "C" void kernel_launch(void* const* d_in, const int* in_sizes, int n_in,
                              void* d_out, int out_size, void* d_ws, size_t ws_size,
                              hipStream_t stream) {
  const float* inputs = (const float*)d_in[0];
  const float* noise  = (const float*)d_in[1];
  const float* mu     = (const float*)d_in[2];
  const float* lsig   = (const float*)d_in[3];
  const float* Wq     = (const float*)d_in[4];
  const float* Wk     = (const float*)d_in[5];
  const float* Wv     = (const float*)d_in[6];
  const float* Wih    = (const float*)d_in[7];
  const float* Whh    = (const float*)d_in[8];
  const float* bih    = (const float*)d_in[9];
  const float* bhh    = (const float*)d_in[10];
  const float* W1     = (const float*)d_in[11];
  const float* b1     = (const float*)d_in[12];
  const float* W2     = (const float*)d_in[13];
  const float* b2     = (const float*)d_in[14];
  const float* gin    = (const float*)d_in[15];
  const float* bein   = (const float*)d_in[16];
  const float* gsl    = (const float*)d_in[17];
  const float* besl   = (const float*)d_in[18];
  const float* gff    = (const float*)d_in[19];
  const float* beff   = (const float*)d_in[20];

  char* ws = (char*)d_ws;
  size_t off = 0;
  auto alloc = [&](size_t bytes) -> void* {
    void* p = ws + off;
    off += (bytes + 255) & ~(size_t)255;
    return p;
  };
  bf16*  xhat    = (bf16*) alloc((size_t)B_ * N_ * 256 * 2);    // 64 MiB
  bf16*  qpad    = (bf16*) alloc((size_t)B_ * SP_ * 256 * 2);
  bf16*  cWkT    = (bf16*) alloc(256 * 256 * 2);
  bf16*  cWvT    = (bf16*) alloc(256 * 256 * 2);
  bf16*  cWq     = (bf16*) alloc(256 * 256 * 2);
  bf16*  cWih    = (bf16*) alloc(768 * 256 * 2);
  bf16*  cWhh    = (bf16*) alloc(768 * 256 * 2);
  bf16*  cW1     = (bf16*) alloc(512 * 256 * 2);
  bf16*  cW2     = (bf16*) alloc(256 * 512 * 2);
  bf16*  Wfold   = (bf16*) alloc(768 * 256 * 2);
  float* slots   = (float*)alloc((size_t)352 * 256 * 4);
  bf16*  slots_bf= (bf16*) alloc((size_t)352 * 256 * 2);
  bf16*  numpart = (bf16*) alloc((size_t)B_ * P_ * NS_ * 256 * 2); // 5.8 MB
  float* denpart = (float*)alloc((size_t)B_ * P_ * NS_ * 4);
  bf16*  u0b     = (bf16*) alloc((size_t)352 * 256 * 2);
  float* hn_f    = (float*)alloc((size_t)352 * 256 * 4);
  bf16*  h1b     = (bf16*) alloc((size_t)352 * 512 * 2);
  (void)ws_size; (void)in_sizes; (void)n_in; (void)out_size;

  cast_weights<<<3328, 256, 0, stream>>>(Wq, Wk, Wv, Wih, Whh, W1, W2,
                                         cWkT, cWvT, cWq, cWih, cWhh, cW1, cW2);
  wfold_gemm<<<dim3(24, 4), 256, 0, stream>>>(cWih, cWvT, Wfold);
  init_slots<<<352, 256, 0, stream>>>(mu, lsig, noise, slots, slots_bf);
  ln_cast<<<2048, 256, 0, stream>>>(inputs, gin, bein, xhat);
  for (int it = 0; it < ITERS_; ++it) {
    q_proj<<<dim3(SP_, B_), 256, 0, stream>>>(slots, gsl, besl, cWq, cWkT, qpad);
    attn_part<<<dim3(P_, B_), 256, 0, stream>>>(xhat, qpad, numpart, denpart);
    u0_reduce<<<352, 256, 0, stream>>>(numpart, denpart, u0b);
    gates_ew<<<dim3(11, 4), 256, 0, stream>>>(u0b, slots_bf, Wfold, cWhh,
                                              bih, bhh, slots, hn_f);
    w1_gemm<<<dim3(11, 8), 256, 0, stream>>>(hn_f, gff, beff, cW1, b1, h1b);
    float* sout = (it == ITERS_ - 1) ? (float*)d_out : slots;
    w2_gemm<<<dim3(11, 4), 256, 0, stream>>>(h1b, cW2, b2, hn_f, sout, slots_bf);
  }
}

// Round 23
// 263.489 us; speedup vs baseline: 1.1850x; 1.1850x over previous
//
#include <hip/hip_runtime.h>
#include <hip/hip_bf16.h>
#include <math.h>

typedef __bf16 bf16;
typedef __bf16 bf16x4 __attribute__((ext_vector_type(4)));
typedef __bf16 bf16x8 __attribute__((ext_vector_type(8)));
typedef float  f32x4  __attribute__((ext_vector_type(4)));

#define DEVI static __device__ __forceinline__

constexpr int B_ = 32, N_ = 4096, NS_ = 11, SP_ = 16, ITERS_ = 3;
constexpr int P_ = 32;
constexpr float LN_EPS_ = 1e-3f;
constexpr float EPS_ATTN_ = 1e-8f;

DEVI f32x4 mfma16(bf16x8 a, bf16x8 b, f32x4 c) {
  return __builtin_amdgcn_mfma_f32_16x16x32_bf16(a, b, c, 0, 0, 0);
}

DEVI float wsum64(float v) {
#pragma unroll
  for (int m = 32; m > 0; m >>= 1) v += __shfl_xor(v, m, 64);
  return v;
}

// ---------------- weight cast (fp32 -> bf16) ----------------
__global__ __launch_bounds__(256) void cast_weights(
    const float* __restrict__ Wq, const float* __restrict__ Wk,
    const float* __restrict__ Wv, const float* __restrict__ Wih,
    const float* __restrict__ Whh, const float* __restrict__ W1,
    const float* __restrict__ W2,
    bf16* __restrict__ cWkT, bf16* __restrict__ cWvT, bf16* __restrict__ cWq,
    bf16* __restrict__ cWih, bf16* __restrict__ cWhh, bf16* __restrict__ cW1,
    bf16* __restrict__ cW2) {
  const int idx = blockIdx.x * 256 + threadIdx.x;
  const int n0 = 256 * 256;            // cWkT (transposed)
  const int n1 = n0 + 256 * 256;       // cWvT (transposed)
  const int n2 = n1 + 256 * 256;       // cWq
  const int n3 = n2 + 768 * 256;       // cWih
  const int n4 = n3 + 768 * 256;       // cWhh
  const int n5 = n4 + 512 * 256;       // cW1
  const int n6 = n5 + 256 * 512;       // cW2   (total 851968 = 3328*256)
  if (idx < n0) {
    const int c = idx >> 8, d = idx & 255;
    cWkT[idx] = (bf16)Wk[d * 256 + c];
  } else if (idx < n1) {
    const int i = idx - n0; const int c = i >> 8, d = i & 255;
    cWvT[i] = (bf16)Wv[d * 256 + c];
  } else if (idx < n2) { const int i = idx - n1; cWq[i]  = (bf16)Wq[i];
  } else if (idx < n3) { const int i = idx - n2; cWih[i] = (bf16)Wih[i];
  } else if (idx < n4) { const int i = idx - n3; cWhh[i] = (bf16)Whh[i];
  } else if (idx < n5) { const int i = idx - n4; cW1[i]  = (bf16)W1[i];
  } else if (idx < n6) { const int i = idx - n5; cW2[i]  = (bf16)W2[i]; }
}

// ---------------- Wfold = Wih @ Wv  (768x256, K=256) ----------------
__global__ __launch_bounds__(256) void wfold_gemm(
    const bf16* __restrict__ Wih, const bf16* __restrict__ WvT,
    bf16* __restrict__ Wfold) {
  __shared__ bf16 At[32 * 256];                  // 16 KiB
  const int mt = blockIdx.x, nt = blockIdx.y;    // (24, 4)
  const int tid = threadIdx.x, lane = tid & 63, wid = tid >> 6;
  const int l15 = lane & 15, gq = lane >> 4;
  const bf16* A = Wih + (size_t)mt * 32 * 256;
#pragma unroll
  for (int i = 0; i < 4; ++i) {
    const int idx = i * 256 + tid, row = idx >> 5, c = idx & 31;
    const bf16x8 v = *(const bf16x8*)(A + row * 256 + c * 8);
    const int byte = (row * 512 + c * 16) ^ ((row & 7) << 4);
    *(bf16x8*)((char*)At + byte) = v;
  }
  __syncthreads();
  const int wr = wid >> 1, wc = wid & 1;
  f32x4 acc[2] = {};
  for (int kk = 0; kk < 8; ++kk) {
    const int arow = wr * 16 + l15;
    const int byte = (arow * 512 + kk * 64 + gq * 16) ^ ((arow & 7) << 4);
    const bf16x8 af = *(const bf16x8*)((const char*)At + byte);
#pragma unroll
    for (int nn = 0; nn < 2; ++nn) {
      const bf16* wrow = WvT + (size_t)(nt * 64 + wc * 32 + nn * 16 + l15) * 256 + kk * 32 + gq * 8;
      acc[nn] = mfma16(af, *(const bf16x8*)wrow, acc[nn]);
    }
  }
#pragma unroll
  for (int nn = 0; nn < 2; ++nn)
#pragma unroll
    for (int r = 0; r < 4; ++r) {
      const int grow = mt * 32 + wr * 16 + gq * 4 + r;
      const int col = nt * 64 + wc * 32 + nn * 16 + l15;
      Wfold[(size_t)grow * 256 + col] = (bf16)acc[nn][r];
    }
}

// ---------------- slot init: fp32 + bf16 copies ----------------
__global__ __launch_bounds__(256) void init_slots(
    const float* __restrict__ mu, const float* __restrict__ lsig,
    const float* __restrict__ noise, float* __restrict__ slots,
    bf16* __restrict__ slots_bf) {
  const int idx = blockIdx.x * 256 + threadIdx.x;  // 90112 exact
  const int d = idx & 255;
  const float v = mu[d] + expf(lsig[d]) * noise[idx];
  slots[idx] = v;
  slots_bf[idx] = (bf16)v;
}

// ---------------- pure-streaming LN: fp32 inputs -> bf16 xhat ----------------
// grid 2048 x 256 thr, grid-stride over row-quads. 16 lanes/row (R12-proven).
__global__ __launch_bounds__(256) void ln_cast(
    const float* __restrict__ inp, const float* __restrict__ g,
    const float* __restrict__ be, bf16* __restrict__ xhat) {
  const int tid = threadIdx.x, lane = tid & 63, wid = tid >> 6;
  const int l15 = lane & 15, gq = lane >> 4;
  float4 gv[4], bv4[4];
#pragma unroll
  for (int u = 0; u < 4; ++u) {
    gv[u]  = ((const float4*)g)[l15 * 4 + u];
    bv4[u] = ((const float4*)be)[l15 * 4 + u];
  }
  const int nwaves = gridDim.x * 4;
  const int gw = blockIdx.x * 4 + wid;
  for (int qi = gw; qi < (B_ * N_ / 4); qi += nwaves) {
    const size_t grow = (size_t)qi * 4 + gq;
    const float4* rp = (const float4*)(inp + grow * 256 + l15 * 16);
    float4 x[4];
#pragma unroll
    for (int u = 0; u < 4; ++u) x[u] = rp[u];
    float s = 0.f, ss = 0.f;
#pragma unroll
    for (int u = 0; u < 4; ++u) {
      s += x[u].x + x[u].y + x[u].z + x[u].w;
      ss = fmaf(x[u].x, x[u].x, fmaf(x[u].y, x[u].y,
           fmaf(x[u].z, x[u].z, fmaf(x[u].w, x[u].w, ss))));
    }
#pragma unroll
    for (int m = 8; m > 0; m >>= 1) {
      s  += __shfl_xor(s,  m, 16);
      ss += __shfl_xor(ss, m, 16);
    }
    const float mean = s * (1.f / 256.f);
    const float rstd = rsqrtf(ss * (1.f / 256.f) - mean * mean + LN_EPS_);
    bf16x8 y0, y1;
#pragma unroll
    for (int u = 0; u < 2; ++u) {
      y0[u * 4 + 0] = (bf16)((x[u].x - mean) * rstd * gv[u].x + bv4[u].x);
      y0[u * 4 + 1] = (bf16)((x[u].y - mean) * rstd * gv[u].y + bv4[u].y);
      y0[u * 4 + 2] = (bf16)((x[u].z - mean) * rstd * gv[u].z + bv4[u].z);
      y0[u * 4 + 3] = (bf16)((x[u].w - mean) * rstd * gv[u].w + bv4[u].w);
      y1[u * 4 + 0] = (bf16)((x[2+u].x - mean) * rstd * gv[2+u].x + bv4[2+u].x);
      y1[u * 4 + 1] = (bf16)((x[2+u].y - mean) * rstd * gv[2+u].y + bv4[2+u].y);
      y1[u * 4 + 2] = (bf16)((x[2+u].z - mean) * rstd * gv[2+u].z + bv4[2+u].z);
      y1[u * 4 + 3] = (bf16)((x[2+u].w - mean) * rstd * gv[2+u].w + bv4[2+u].w);
    }
    bf16* orow = xhat + grow * 256 + l15 * 16;
    *(bf16x8*)orow       = y0;
    *(bf16x8*)(orow + 8) = y1;
  }
}

// ---------------- q~ projection: LN(slots) @ Wq^T @ Wk ----------------
__global__ __launch_bounds__(256) void q_proj(
    const float* __restrict__ slots, const float* __restrict__ g,
    const float* __restrict__ be, const bf16* __restrict__ Wqb,
    const bf16* __restrict__ WkT, bf16* __restrict__ qpad) {
  const int i = blockIdx.x, b = blockIdx.y, t = threadIdx.x;
  bf16* out = qpad + (b * SP_ + i) * 256;
  if (i >= NS_) { out[t] = (bf16)0.f; return; }
  __shared__ float lnv[256], qd[256];
  __shared__ float red[8];
  const float x = slots[(b * NS_ + i) * 256 + t];
  float s = wsum64(x), ss = wsum64(x * x);
  const int lane = t & 63, w = t >> 6;
  if (lane == 0) { red[w] = s; red[4 + w] = ss; }
  __syncthreads();
  const float st = red[0] + red[1] + red[2] + red[3];
  const float qt = red[4] + red[5] + red[6] + red[7];
  const float mean = st / 256.f, var = qt / 256.f - mean * mean;
  const float rstd = rsqrtf(var + LN_EPS_);
  lnv[t] = (x - mean) * rstd * g[t] + be[t];
  __syncthreads();
  {
    float acc = 0.f;
    const bf16* wr = Wqb + (size_t)t * 256;
    for (int it = 0; it < 32; ++it) {
      const bf16x8 wv = *(const bf16x8*)(wr + it * 8);
      const float* u = &lnv[it * 8];
#pragma unroll
      for (int e = 0; e < 8; ++e) acc += (float)wv[e] * u[e];
    }
    qd[t] = acc;
  }
  __syncthreads();
  {
    float acc = 0.f;
    const bf16* wr = WkT + (size_t)t * 256;
    for (int it = 0; it < 32; ++it) {
      const bf16x8 wv = *(const bf16x8*)(wr + it * 8);
      const float* u = &qd[it * 8];
#pragma unroll
      for (int e = 0; e < 8; ++e) acc += (float)wv[e] * u[e];
    }
    out[t] = (bf16)(acc * 0.0625f);
  }
}

// ---------------- fused attention partial pass (V staged from xhat) --------
// grid (P_, B), 256 threads; per-wave LDS V staging (R2-proven pattern),
// c processed in two 128-halves; bf16 num_part.
__global__ __launch_bounds__(256) void attn_part(
    const bf16* __restrict__ xhat, const bf16* __restrict__ qpad,
    bf16* __restrict__ num_part, float* __restrict__ den_part) {
  const int part = blockIdx.x, b = blockIdx.y;
  const int lane = threadIdx.x & 63, wid = threadIdx.x >> 6;
  const int l15 = lane & 15, gq = lane >> 4;
  const int jbase = part * 128 + wid * 32;
  const bf16* qrow = qpad + ((size_t)(b * SP_ + l15)) * 256;
  const bf16* kbase = xhat + ((size_t)(b * N_ + jbase)) * 256;
  __shared__ bf16 vlds[4][4096];                 // 32 KiB (8 KiB / wave)
  __shared__ float nsw[2][4096];                 // 32 KiB
  __shared__ float dens[4][16];
  char* myv = (char*)&vlds[wid][0];
  const int srow = gq;

  // issue V half-0 loads (c 0..127): hidden under QK^T
  bf16x8 vst[8];
#pragma unroll
  for (int i = 0; i < 8; ++i)
    vst[i] = *(const bf16x8*)(kbase + (size_t)(i * 4 + srow) * 256 + l15 * 8);
  // hoisted q fragments
  bf16x8 bq[8];
#pragma unroll
  for (int kk = 0; kk < 8; ++kk)
    bq[kk] = *(const bf16x8*)(qrow + kk * 32 + gq * 8);

  float denacc = 0.f;
  float p0[4], p1[4];
#pragma unroll
  for (int T = 0; T < 2; ++T) {
    const bf16* krow = kbase + (size_t)(T * 16 + l15) * 256;
    f32x4 d = {0.f, 0.f, 0.f, 0.f};
#pragma unroll
    for (int kk = 0; kk < 8; ++kk) {
      const bf16x8 ak = *(const bf16x8*)(krow + kk * 32 + gq * 8);
      d = mfma16(ak, bq[kk], d);
    }
    // softmax over slots i = l15 (across 16-lane groups), per j-row reg
#pragma unroll
    for (int r = 0; r < 4; ++r) {
      float vmax = (l15 < NS_) ? d[r] : -1e30f;
#pragma unroll
      for (int mm = 8; mm > 0; mm >>= 1) vmax = fmaxf(vmax, __shfl_xor(vmax, mm, 16));
      const float e = (l15 < NS_) ? expf(d[r] - vmax) : 0.f;
      float ssum = e;
#pragma unroll
      for (int mm = 8; mm > 0; mm >>= 1) ssum += __shfl_xor(ssum, mm, 16);
      const float p = (l15 < NS_) ? (e / ssum + EPS_ATTN_) : 0.f;
      if (T == 0) p0[r] = p; else p1[r] = p;
      denacc += p;
    }
  }
  // regather P into A-frag layout: ap[e] = P[i=l15][j-local = 8*gq+e]
  bf16x8 ap;
#pragma unroll
  for (int e = 0; e < 8; ++e) {
    const int srcl = l15 + ((2 * (gq & 1) + (e >> 2)) << 4);
    const float va = __shfl(p0[e & 3], srcl, 64);
    const float vb = __shfl(p1[e & 3], srcl, 64);
    ap[e] = (bf16)((gq < 2) ? va : vb);
  }
  // --- PV with V through per-wave swizzled LDS, two c-halves of 128 ---
  f32x4 accN[16];
#pragma unroll
  for (int i = 0; i < 8; ++i) {                  // ds_write half 0
    const int row = i * 4 + srow;
    const int byte = (row * 256 + l15 * 16) ^ ((((row >> 3) & 3)) << 5);
    *(bf16x8*)(myv + byte) = vst[i];
  }
#pragma unroll
  for (int i = 0; i < 8; ++i)                    // issue half-1 loads
    vst[i] = *(const bf16x8*)(kbase + (size_t)(i * 4 + srow) * 256 + 128 + l15 * 8);
  __builtin_amdgcn_s_setprio(1);
#pragma unroll
  for (int l = 0; l < 8; ++l) {                  // PV c-blk 0..7
    bf16x8 bvf;
#pragma unroll
    for (int e = 0; e < 8; ++e) {
      const int row = 8 * gq + e;
      const int byte = (row * 256 + l * 32 + l15 * 2) ^ ((((row >> 3) & 3)) << 5);
      bvf[e] = *(const bf16*)(myv + byte);
    }
    f32x4 z = {0.f, 0.f, 0.f, 0.f};
    accN[l] = mfma16(ap, bvf, z);
  }
  __builtin_amdgcn_s_setprio(0);
#pragma unroll
  for (int i = 0; i < 8; ++i) {                  // ds_write half 1
    const int row = i * 4 + srow;
    const int byte = (row * 256 + l15 * 16) ^ ((((row >> 3) & 3)) << 5);
    *(bf16x8*)(myv + byte) = vst[i];
  }
  __builtin_amdgcn_s_setprio(1);
#pragma unroll
  for (int l = 0; l < 8; ++l) {                  // PV c-blk 8..15
    bf16x8 bvf;
#pragma unroll
    for (int e = 0; e < 8; ++e) {
      const int row = 8 * gq + e;
      const int byte = (row * 256 + l * 32 + l15 * 2) ^ ((((row >> 3) & 3)) << 5);
      bvf[e] = *(const bf16*)(myv + byte);
    }
    f32x4 z = {0.f, 0.f, 0.f, 0.f};
    accN[8 + l] = mfma16(ap, bvf, z);
  }
  __builtin_amdgcn_s_setprio(0);
  // cross-wave reduce: 2-buffer log tree (2 barriers)
  if (wid < 2) {
#pragma unroll
    for (int dblk = 0; dblk < 16; ++dblk)
#pragma unroll
      for (int r = 0; r < 4; ++r) {
        const int idx = (((4 * gq + r) * 256) + dblk * 16 + l15) ^ (gq << 4);
        nsw[wid][idx] = accN[dblk][r];
      }
  }
  __syncthreads();
  if (wid >= 2) {
#pragma unroll
    for (int dblk = 0; dblk < 16; ++dblk)
#pragma unroll
      for (int r = 0; r < 4; ++r) {
        const int idx = (((4 * gq + r) * 256) + dblk * 16 + l15) ^ (gq << 4);
        nsw[wid - 2][idx] += accN[dblk][r];
      }
  }
  float dtot = denacc + __shfl_xor(denacc, 16, 64);
  dtot += __shfl_xor(dtot, 32, 64);
  if (lane < 16) dens[wid][l15] = dtot;
  __syncthreads();
  const int t = threadIdx.x;
  if (t < NS_)
    den_part[(b * P_ + part) * NS_ + t] =
        dens[0][t] + dens[1][t] + dens[2][t] + dens[3][t];
  for (int r = 0; r < NS_; ++r) {
    const int swz = ((r >> 2) & 3) << 4;
    num_part[((size_t)((b * P_ + part) * NS_ + r)) * 256 + t] =
        (bf16)(nsw[0][(r * 256 + t) ^ swz] + nsw[1][(r * 256 + t) ^ swz]);
  }
}

// ---------------- u0 reduce: bf16 num_part/den -> bf16 (352x256) -----------
__global__ __launch_bounds__(256) void u0_reduce(
    const bf16* __restrict__ num_part, const float* __restrict__ den_part,
    bf16* __restrict__ u0b) {
  const int row = blockIdx.x, t = threadIdx.x;
  const int b = row / NS_, i = row % NS_;
  float nsum = 0.f;
  for (int p = 0; p < P_; ++p)
    nsum += (float)num_part[((size_t)((b * P_ + p) * NS_ + i)) * 256 + t];
  float den = 0.f;
  for (int p = 0; p < P_; ++p) den += den_part[(b * P_ + p) * NS_ + i];
  u0b[(size_t)row * 256 + t] = (bf16)(nsum / den);
}

// ---------------- gates GEMM: gi = u0@Wfold^T ; gh = h@Whh^T ----------------
__global__ __launch_bounds__(256) void gates_gemm(
    const bf16* __restrict__ u0b, const bf16* __restrict__ hb,
    const bf16* __restrict__ Wfold, const bf16* __restrict__ Whh,
    float* __restrict__ gi, float* __restrict__ gh) {
  __shared__ bf16 At[32 * 256];                  // 16 KiB
  const int mt = blockIdx.x, nt = blockIdx.y;
  const bool isI = nt < 12;
  const int ntile = isI ? nt : nt - 12;
  const bf16* A = (isI ? u0b : hb) + (size_t)mt * 32 * 256;
  const bf16* W = isI ? Wfold : Whh;
  float* out = isI ? gi : gh;
  const int tid = threadIdx.x, lane = tid & 63, wid = tid >> 6;
  const int l15 = lane & 15, gq = lane >> 4;
#pragma unroll
  for (int i = 0; i < 4; ++i) {
    const int idx = i * 256 + tid, row = idx >> 5, c = idx & 31;
    const bf16x8 v = *(const bf16x8*)(A + row * 256 + c * 8);
    const int byte = (row * 512 + c * 16) ^ ((row & 7) << 4);
    *(bf16x8*)((char*)At + byte) = v;
  }
  __syncthreads();
  const int wr = wid >> 1, wc = wid & 1;
  f32x4 acc[2] = {};
  for (int kk = 0; kk < 8; ++kk) {
    const int arow = wr * 16 + l15;
    const int byte = (arow * 512 + kk * 64 + gq * 16) ^ ((arow & 7) << 4);
    const bf16x8 af = *(const bf16x8*)((const char*)At + byte);
#pragma unroll
    for (int nn = 0; nn < 2; ++nn) {
      const bf16* wrow = W + (size_t)(ntile * 64 + wc * 32 + nn * 16 + l15) * 256 + kk * 32 + gq * 8;
      acc[nn] = mfma16(af, *(const bf16x8*)wrow, acc[nn]);
    }
  }
#pragma unroll
  for (int nn = 0; nn < 2; ++nn)
#pragma unroll
    for (int r = 0; r < 4; ++r) {
      const int grow = mt * 32 + wr * 16 + gq * 4 + r;
      const int col = ntile * 64 + wc * 32 + nn * 16 + l15;
      out[(size_t)grow * 768 + col] = acc[nn][r];
    }
}

// ---------------- elementwise GRU + LN ----------------
__global__ __launch_bounds__(256) void gru_ew(
    const float* __restrict__ gi, const float* __restrict__ gh,
    const float* __restrict__ bih, const float* __restrict__ bhh,
    const float* __restrict__ slots_f, const float* __restrict__ gff,
    const float* __restrict__ beff, float* __restrict__ hn_out,
    bf16* __restrict__ ln_out) {
  const int row = blockIdx.x, t = threadIdx.x;
  __shared__ float red[8];
  const size_t g0 = (size_t)row * 768;
  const float ir = gi[g0 + t]       + bih[t];
  const float hr = gh[g0 + t]       + bhh[t];
  const float iz = gi[g0 + 256 + t] + bih[256 + t];
  const float hz = gh[g0 + 256 + t] + bhh[256 + t];
  const float inn = gi[g0 + 512 + t] + bih[512 + t];
  const float hnn = gh[g0 + 512 + t] + bhh[512 + t];
  const float h = slots_f[(size_t)row * 256 + t];
  const float r = 1.f / (1.f + expf(-(ir + hr)));
  const float z = 1.f / (1.f + expf(-(iz + hz)));
  const float n = tanhf(inn + r * hnn);
  const float hn = (1.f - z) * n + z * h;
  hn_out[(size_t)row * 256 + t] = hn;
  float s = wsum64(hn), ss = wsum64(hn * hn);
  const int lane = t & 63, w = t >> 6;
  if (lane == 0) { red[w] = s; red[4 + w] = ss; }
  __syncthreads();
  const float st = red[0] + red[1] + red[2] + red[3];
  const float qt = red[4] + red[5] + red[6] + red[7];
  const float mean = st / 256.f, var = qt / 256.f - mean * mean;
  const float rstd = rsqrtf(var + LN_EPS_);
  ln_out[(size_t)row * 256 + t] = (bf16)((hn - mean) * rstd * gff[t] + beff[t]);
}

// ---------------- W1 GEMM: h1 = relu(ln@W1^T + b1), bf16 ----------------
__global__ __launch_bounds__(256) void w1_gemm(
    const bf16* __restrict__ lnb, const bf16* __restrict__ W1,
    const float* __restrict__ b1, bf16* __restrict__ h1b) {
  __shared__ bf16 At[32 * 256];
  const int mt = blockIdx.x, nt = blockIdx.y;    // (11, 8)
  const int tid = threadIdx.x, lane = tid & 63, wid = tid >> 6;
  const int l15 = lane & 15, gq = lane >> 4;
  const bf16* A = lnb + (size_t)mt * 32 * 256;
#pragma unroll
  for (int i = 0; i < 4; ++i) {
    const int idx = i * 256 + tid, row = idx >> 5, c = idx & 31;
    const bf16x8 v = *(const bf16x8*)(A + row * 256 + c * 8);
    const int byte = (row * 512 + c * 16) ^ ((row & 7) << 4);
    *(bf16x8*)((char*)At + byte) = v;
  }
  __syncthreads();
  const int wr = wid >> 1, wc = wid & 1;
  f32x4 acc[2] = {};
  for (int kk = 0; kk < 8; ++kk) {
    const int arow = wr * 16 + l15;
    const int byte = (arow * 512 + kk * 64 + gq * 16) ^ ((arow & 7) << 4);
    const bf16x8 af = *(const bf16x8*)((const char*)At + byte);
#pragma unroll
    for (int nn = 0; nn < 2; ++nn) {
      const bf16* wrow = W1 + (size_t)(nt * 64 + wc * 32 + nn * 16 + l15) * 256 + kk * 32 + gq * 8;
      acc[nn] = mfma16(af, *(const bf16x8*)wrow, acc[nn]);
    }
  }
#pragma unroll
  for (int nn = 0; nn < 2; ++nn)
#pragma unroll
    for (int r = 0; r < 4; ++r) {
      const int grow = mt * 32 + wr * 16 + gq * 4 + r;
      const int col = nt * 64 + wc * 32 + nn * 16 + l15;
      h1b[(size_t)grow * 512 + col] = (bf16)fmaxf(acc[nn][r] + b1[col], 0.f);
    }
}

// ---------------- W2 GEMM (K=512): out = hn + h1@W2^T + b2 ----------------
__global__ __launch_bounds__(256) void w2_gemm(
    const bf16* __restrict__ h1b, const bf16* __restrict__ W2,
    const float* __restrict__ b2, const float* __restrict__ hn_in,
    float* __restrict__ sout, bf16* __restrict__ sbf) {
  __shared__ bf16 At[32 * 512];                  // 32 KiB
  const int mt = blockIdx.x, nt = blockIdx.y;    // (11, 4)
  const int tid = threadIdx.x, lane = tid & 63, wid = tid >> 6;
  const int l15 = lane & 15, gq = lane >> 4;
  const bf16* A = h1b + (size_t)mt * 32 * 512;
#pragma unroll
  for (int i = 0; i < 8; ++i) {
    const int idx = i * 256 + tid, row = idx >> 6, c = idx & 63;
    const bf16x8 v = *(const bf16x8*)(A + row * 512 + c * 8);
    const int byte = (row * 1024 + c * 16) ^ ((row & 7) << 4);
    *(bf16x8*)((char*)At + byte) = v;
  }
  __syncthreads();
  const int wr = wid >> 1, wc = wid & 1;
  f32x4 acc[2] = {};
  for (int kk = 0; kk < 16; ++kk) {
    const int arow = wr * 16 + l15;
    const int byte = (arow * 1024 + kk * 64 + gq * 16) ^ ((arow & 7) << 4);
    const bf16x8 af = *(const bf16x8*)((const char*)At + byte);
#pragma unroll
    for (int nn = 0; nn < 2; ++nn) {
      const bf16* wrow = W2 + (size_t)(nt * 64 + wc * 32 + nn * 16 + l15) * 512 + kk * 32 + gq * 8;
      acc[nn] = mfma16(af, *(const bf16x8*)wrow, acc[nn]);
    }
  }
#pragma unroll
  for (int nn = 0; nn < 2; ++nn)
#pragma unroll
    for (int r = 0; r < 4; ++r) {
      const int grow = mt * 32 + wr * 16 + gq * 4 + r;
      const int col = nt * 64 + wc * 32 + nn * 16 + l15;
      const float v = hn_in[(size_t)grow * 256 + col] + acc[nn][r] + b2[col];
      sout[(size_t)grow * 256 + col] = v;
      sbf[(size_t)grow * 256 + col] = (bf16)v;
    }
}

// ---------------- launcher ----------------
extern "C" void kernel_launch(void* const* d_in, const int* in_sizes, int n_in,
                              void* d_out, int out_size, void* d_ws, size_t ws_size,
                              hipStream_t stream) {
  const float* inputs = (const float*)d_in[0];
  const float* noise  = (const float*)d_in[1];
  const float* mu     = (const float*)d_in[2];
  const float* lsig   = (const float*)d_in[3];
  const float* Wq     = (const float*)d_in[4];
  const float* Wk     = (const float*)d_in[5];
  const float* Wv     = (const float*)d_in[6];
  const float* Wih    = (const float*)d_in[7];
  const float* Whh    = (const float*)d_in[8];
  const float* bih    = (const float*)d_in[9];
  const float* bhh    = (const float*)d_in[10];
  const float* W1     = (const float*)d_in[11];
  const float* b1     = (const float*)d_in[12];
  const float* W2     = (const float*)d_in[13];
  const float* b2     = (const float*)d_in[14];
  const float* gin    = (const float*)d_in[15];
  const float* bein   = (const float*)d_in[16];
  const float* gsl    = (const float*)d_in[17];
  const float* besl   = (const float*)d_in[18];
  const float* gff    = (const float*)d_in[19];
  const float* beff   = (const float*)d_in[20];

  char* ws = (char*)d_ws;
  size_t off = 0;
  auto alloc = [&](size_t bytes) -> void* {
    void* p = ws + off;
    off += (bytes + 255) & ~(size_t)255;
    return p;
  };
  bf16*  xhat    = (bf16*) alloc((size_t)B_ * N_ * 256 * 2);    // 64 MiB
  bf16*  qpad    = (bf16*) alloc((size_t)B_ * SP_ * 256 * 2);
  bf16*  cWkT    = (bf16*) alloc(256 * 256 * 2);
  bf16*  cWvT    = (bf16*) alloc(256 * 256 * 2);
  bf16*  cWq     = (bf16*) alloc(256 * 256 * 2);
  bf16*  cWih    = (bf16*) alloc(768 * 256 * 2);
  bf16*  cWhh    = (bf16*) alloc(768 * 256 * 2);
  bf16*  cW1     = (bf16*) alloc(512 * 256 * 2);
  bf16*  cW2     = (bf16*) alloc(256 * 512 * 2);
  bf16*  Wfold   = (bf16*) alloc(768 * 256 * 2);
  float* slots   = (float*)alloc((size_t)352 * 256 * 4);
  bf16*  slots_bf= (bf16*) alloc((size_t)352 * 256 * 2);
  bf16*  numpart = (bf16*) alloc((size_t)B_ * P_ * NS_ * 256 * 2); // 5.8 MB
  float* denpart = (float*)alloc((size_t)B_ * P_ * NS_ * 4);
  bf16*  u0b     = (bf16*) alloc((size_t)352 * 256 * 2);
  float* gi      = (float*)alloc((size_t)352 * 768 * 4);
  float* gh      = (float*)alloc((size_t)352 * 768 * 4);
  float* hn_f    = (float*)alloc((size_t)352 * 256 * 4);
  bf16*  ln_b    = (bf16*) alloc((size_t)352 * 256 * 2);
  bf16*  h1b     = (bf16*) alloc((size_t)352 * 512 * 2);
  (void)ws_size; (void)in_sizes; (void)n_in; (void)out_size;

  cast_weights<<<3328, 256, 0, stream>>>(Wq, Wk, Wv, Wih, Whh, W1, W2,
                                         cWkT, cWvT, cWq, cWih, cWhh, cW1, cW2);
  wfold_gemm<<<dim3(24, 4), 256, 0, stream>>>(cWih, cWvT, Wfold);
  init_slots<<<352, 256, 0, stream>>>(mu, lsig, noise, slots, slots_bf);
  ln_cast<<<2048, 256, 0, stream>>>(inputs, gin, bein, xhat);
  for (int it = 0; it < ITERS_; ++it) {
    q_proj<<<dim3(SP_, B_), 256, 0, stream>>>(slots, gsl, besl, cWq, cWkT, qpad);
    attn_part<<<dim3(P_, B_), 256, 0, stream>>>(xhat, qpad, numpart, denpart);
    u0_reduce<<<352, 256, 0, stream>>>(numpart, denpart, u0b);
    gates_gemm<<<dim3(11, 24), 256, 0, stream>>>(u0b, slots_bf, Wfold, cWhh, gi, gh);
    gru_ew<<<352, 256, 0, stream>>>(gi, gh, bih, bhh, slots, gff, beff, hn_f, ln_b);
    w1_gemm<<<dim3(11, 8), 256, 0, stream>>>(ln_b, cW1, b1, h1b);
    float* sout = (it == ITERS_ - 1) ? (float*)d_out : slots;
    w2_gemm<<<dim3(11, 4), 256, 0, stream>>>(h1b, cW2, b2, hn_f, sout, slots_bf);
  }
}